// Round 1
// 795.306 us; speedup vs baseline: 1.2892x; 1.2892x over previous
//
#include <hip/hip_runtime.h>
#include <cstddef>
#include <cstdint>

#define NBATCH 8
#define NPTS   2048
#define KNN    20

typedef __attribute__((ext_vector_type(8))) short short8;
typedef __attribute__((ext_vector_type(4))) float f32x4;

__device__ __forceinline__ unsigned short f2bf(float f) {
  unsigned u = __float_as_uint(f);
  u += 0x7fff + ((u >> 16) & 1);   // round-to-nearest-even
  return (unsigned short)(u >> 16);
}
__device__ __forceinline__ float bf2f(unsigned short h) {
  return __uint_as_float(((unsigned)h) << 16);
}

// monotone float -> orderable uint (ascending uint == ascending float)
__device__ __forceinline__ unsigned f2ord(float f) {
  unsigned u = __float_as_uint(f);
  return (u & 0x80000000u) ? ~u : (u | 0x80000000u);
}

// ---------------------------------------------------------------------------
// 64-lane bitonic sort, ascending across lanes. 21 compare-exchange stages.
// ---------------------------------------------------------------------------
template <typename T>
__device__ __forceinline__ T bitonic_sort_asc(T key, int lane) {
#pragma unroll
  for (int k = 2; k <= 64; k <<= 1) {
#pragma unroll
    for (int j = k >> 1; j > 0; j >>= 1) {
      T other = __shfl_xor(key, j);
      bool takemax = ((lane & k) == 0) != ((lane & j) == 0);
      key = takemax ? (key > other ? key : other)
                    : (key < other ? key : other);
    }
  }
  return key;
}

// ---------------------------------------------------------------------------
// exact serial fallback (ord-space port of the R15 top-2-cache extractor).
// Only taken when >64 values tie above the threshold -- effectively never.
// ---------------------------------------------------------------------------
__device__ void wave_top20_serial(const unsigned (&v)[32], int lane,
                                  int* __restrict__ row_out) {
  unsigned m1 = 0, m2 = 0;
  int i1 = 0, i2 = 0;
#pragma unroll
  for (int i = 0; i < 32; i++) {
    unsigned x = v[i];
    if (x > m1) { m2 = m1; i2 = i1; m1 = x; i1 = i; }
    else if (x > m2) { m2 = x; i2 = i; }
  }

  unsigned dm = 0;
  int cnt = 2;
  int keep = 0;
  for (int k = 0; k < KNN; k++) {
    unsigned rv = m1;
    int ri = i1 * 64 + lane;
#pragma unroll
    for (int off = 32; off > 0; off >>= 1) {
      unsigned ov = __shfl_down(rv, off);
      int oi = __shfl_down(ri, off);
      if (ov > rv || (ov == rv && oi < ri)) { rv = ov; ri = oi; }
    }
    int wi = __shfl(ri, 0);
    if (lane == k) keep = wi;
    if ((wi & 63) == lane) {
      dm |= 1u << (wi >> 6);
      if (cnt == 2) {
        m1 = m2; i1 = i2; cnt = 1;
      } else {
        m1 = 0; i1 = 0; m2 = 0; i2 = 0;
#pragma unroll
        for (int i = 0; i < 32; i++)
          if (!((dm >> i) & 1)) {
            unsigned x = v[i];
            if (x > m1) { m2 = m1; i2 = i1; m1 = x; i1 = i; }
            else if (x > m2) { m2 = x; i2 = i; }
          }
        cnt = 2;
      }
    }
  }
  if (lane < KNN) row_out[lane] = keep;
}

// ---------------------------------------------------------------------------
// wave-level exact top-20 over 2048 candidates (ord space): lane holds 32
// values, global index of v[i] on lane l is i*64 + l. One wave per row.
// R17: threshold (20th-largest lane max, provable lower bound on the 20th-
// largest overall) -> ballot-compact candidates (~24 expected) into LDS ->
// one 64-lane bitonic sort of packed (value, ~index) keys emits the top-20
// in order with the lowest-index tie-break. Replaces 20 serial shfl-argmax
// rounds (~240 dependent bpermutes) with ~65 bpermutes, no divergent scans.
// cand: 64-slot per-wave LDS scratch.
// ---------------------------------------------------------------------------
__device__ __forceinline__ void wave_top20(const unsigned (&v)[32], int lane,
                                           unsigned long long* cand,
                                           int* __restrict__ row_out) {
  // 1. per-lane max
  unsigned mo = 0;
#pragma unroll
  for (int i = 0; i < 32; i++) mo = (v[i] > mo) ? v[i] : mo;

  // 2. sort the 64 lane maxima; T = 20th largest (ascending lane 44).
  //    >=20 lanes have max >= T, each contributes >=1 value -> >=20 candidates.
  unsigned ms = bitonic_sort_asc(mo, lane);
  unsigned T = __shfl(ms, 64 - KNN);

  // 3. ballot-compact all values >= T into LDS (position order irrelevant;
  //    the final sort orders them). Pad slots stay 0 (< any real ord value).
  cand[lane] = 0ull;
  int base = 0;
#pragma unroll
  for (int i = 0; i < 32; i++) {
    bool p = v[i] >= T;
    unsigned long long mk = __ballot(p);
    if (p) {
      int pos = base + __popcll(mk & ((1ull << lane) - 1ull));
      if (pos < 64)
        cand[pos] = ((unsigned long long)v[i] << 32) |
                    (unsigned)(~(unsigned)(i * 64 + lane));
    }
    base += (int)__popcll(mk);
  }

  if (base <= 64) {
    // 4. one bitonic sort of packed keys; key = (ord << 32) | ~idx so
    //    ascending-key == ascending (value, then index DESCENDING) ->
    //    reading from the top lane downward gives descending value with
    //    lowest-index-first tie-break, matching jax.lax.top_k.
    unsigned long long key = cand[lane];
    key = bitonic_sort_asc(key, lane);
    if (lane >= 64 - KNN)
      row_out[63 - lane] = (int)(~(unsigned)key);
  } else {
    // exact fallback (massive ties above threshold)
    wave_top20_serial(v, lane, row_out);
  }
}

// ---------------------------------------------------------------------------
// transpose (B,3,N) -> (B,N,3)
// ---------------------------------------------------------------------------
__global__ void k_transpose(const float* __restrict__ x, float* __restrict__ h0) {
  int i = blockIdx.x * 256 + threadIdx.x;
  if (i >= NBATCH * NPTS * 3) return;
  int c = i % 3;
  int n = (i / 3) % NPTS;
  int b = i / (3 * NPTS);
  h0[i] = x[((size_t)b * 3 + c) * NPTS + n];
}

// ---------------------------------------------------------------------------
// pairwise "distance" pd = 2*dot - sq_n - sq_m. blockIdx.z = batch in group.
// R11-proven 64x64 tile / 4x4 microtile, upper-triangular grid (528 blocks);
// off-diagonal blocks mirror their tile via an LDS bounce (bit-identical).
// NOTE (R12/R13 lesson): no 8x8 microtile, no waves/EU pin -- both spilled.
// ---------------------------------------------------------------------------
template <int C>
__global__ __launch_bounds__(256) void k_dist(const float* __restrict__ xg,
                                              float* __restrict__ dist) {
  constexpr int PAD = 4;
  constexpr int S = C + PAD;
  constexpr int TS = 67;
  __shared__ __attribute__((aligned(16))) float rows[64 * S];
  __shared__ __attribute__((aligned(16))) float cols[64 * S];
  __shared__ float sq[128];

  const float* xb = xg + (size_t)blockIdx.z * NPTS * C;
  float* db = dist + (size_t)blockIdx.z * NPTS * NPTS;

  constexpr int T = NPTS / 64;
  int bid = blockIdx.x;
  int rt = 0;
  while (bid >= T - rt) { bid -= T - rt; rt++; }
  const int ct = rt + bid;

  const int tid = threadIdx.x;

  for (int e = tid; e < 64 * C; e += 256) {
    int i = e / C, c = e - i * C;
    rows[i * S + c] = xb[(size_t)(rt * 64 + i) * C + c];
    cols[i * S + c] = xb[(size_t)(ct * 64 + i) * C + c];
  }
  __syncthreads();
  if (tid < 128) {
    const float* p = (tid < 64) ? (rows + tid * S) : (cols + (tid - 64) * S);
    float s = 0.f;
    for (int c = 0; c < C; c++) s += p[c] * p[c];
    sq[tid] = s;
  }
  __syncthreads();

  const int r0 = (tid >> 4) * 4;
  const int c0 = tid & 15;
  float acc[4][4] = {};

  for (int c = 0; c < C; c += 4) {
    float4 ra[4], cb[4];
#pragma unroll
    for (int i = 0; i < 4; i++) ra[i] = *(const float4*)&rows[(r0 + i) * S + c];
#pragma unroll
    for (int j = 0; j < 4; j++) cb[j] = *(const float4*)&cols[(c0 + 16 * j) * S + c];
#pragma unroll
    for (int i = 0; i < 4; i++)
#pragma unroll
      for (int j = 0; j < 4; j++)
        acc[i][j] += ra[i].x * cb[j].x + ra[i].y * cb[j].y +
                     ra[i].z * cb[j].z + ra[i].w * cb[j].w;
  }

  float pd[4][4];
#pragma unroll
  for (int i = 0; i < 4; i++) {
    float sr = sq[r0 + i];
#pragma unroll
    for (int j = 0; j < 4; j++)
      pd[i][j] = 2.f * acc[i][j] - sr - sq[64 + c0 + 16 * j];
  }

#pragma unroll
  for (int i = 0; i < 4; i++)
#pragma unroll
    for (int j = 0; j < 4; j++)
      db[(size_t)(rt * 64 + r0 + i) * NPTS + ct * 64 + c0 + 16 * j] = pd[i][j];

  if (rt != ct) {
    __syncthreads();
    float* tb = rows;
#pragma unroll
    for (int i = 0; i < 4; i++)
#pragma unroll
      for (int j = 0; j < 4; j++)
        tb[(c0 + 16 * j) * TS + r0 + i] = pd[i][j];
    __syncthreads();
#pragma unroll
    for (int i = 0; i < 4; i++)
#pragma unroll
      for (int j = 0; j < 4; j++)
        db[(size_t)(ct * 64 + r0 + i) * NPTS + rt * 64 + c0 + 16 * j] =
            tb[(r0 + i) * TS + c0 + 16 * j];
  }
}

// ---------------------------------------------------------------------------
// top-20 per row from materialized dist. One wave per row, 4 rows per block.
// ---------------------------------------------------------------------------
__global__ __launch_bounds__(256) void k_topk(const float* __restrict__ dist,
                                              int* __restrict__ idx_out) {
  __shared__ unsigned long long cand[4][64];
  const int wid = threadIdx.x >> 6;
  const int lane = threadIdx.x & 63;
  const int n = blockIdx.x * 4 + wid;
  const int z = blockIdx.y;
  const float* drow = dist + ((size_t)z * NPTS + n) * NPTS;
  int* row_out = idx_out + ((size_t)z * NPTS + n) * KNN;

  unsigned v[32];
#pragma unroll
  for (int i = 0; i < 32; i++) v[i] = f2ord(drow[i * 64 + lane]);

  wave_top20(v, lane, cand[wid], row_out);
}

// ---------------------------------------------------------------------------
// conv1 fused kNN (C=3): one wave per row, register recompute + wave_top20.
// ---------------------------------------------------------------------------
__global__ __launch_bounds__(256) void k_knn3(const float* __restrict__ x,
                                              int* __restrict__ idx_out) {
  __shared__ unsigned long long cand[4][64];
  const int wid = threadIdx.x >> 6;
  const int lane = threadIdx.x & 63;
  const int n = blockIdx.x * 4 + wid;
  const int b = blockIdx.y;
  const float* xb = x + (size_t)b * NPTS * 3;
  int* row_out = idx_out + ((size_t)b * NPTS + n) * KNN;

  const float qx = xb[n * 3 + 0], qy = xb[n * 3 + 1], qz = xb[n * 3 + 2];
  float qsq = 0.f;
  qsq += qx * qx; qsq += qy * qy; qsq += qz * qz;

  unsigned v[32];
#pragma unroll
  for (int i = 0; i < 32; i++) {
    int m = i * 64 + lane;
    float cx = xb[m * 3 + 0], cy = xb[m * 3 + 1], cz = xb[m * 3 + 2];
    float csq = 0.f;
    csq += cx * cx; csq += cy * cy; csq += cz * cz;
    float acc = 0.f;
    acc += qx * cx; acc += qy * cy; acc += qz * cz;
    v[i] = f2ord(2.f * acc - qsq - csq);
  }

  wave_top20(v, lane, cand[wid], row_out);
}

// ---------------------------------------------------------------------------
// t0 GEMM: t0buf[n, o] = sum_c x[n, c] * w[C+c, o]   (center @ w_hi)
// ---------------------------------------------------------------------------
template <int C, int O>
__global__ __launch_bounds__(256) void k_t0(const float* __restrict__ x,
                                            const float* __restrict__ w,
                                            float* __restrict__ t0buf) {
  constexpr int TM = 128, TN = 64, TK = 16;
  __shared__ __attribute__((aligned(16))) float As[TK][TM + 4];
  __shared__ __attribute__((aligned(16))) float Bs[TK][TN + 4];
  const int mt = blockIdx.x, nt = blockIdx.y;
  const int tid = threadIdx.x;
  const int tx = tid & 15, ty = tid >> 4;
  const size_t m0 = (size_t)mt * TM;
  const int n0 = nt * TN;
  float acc[8][4] = {};

  for (int kt = 0; kt < C; kt += TK) {
#pragma unroll
    for (int e = 0; e < 8; e++) {
      int idx = tid + e * 256;
      int m = idx >> 4, k = idx & 15;
      As[k][m] = x[(m0 + m) * C + kt + k];
    }
#pragma unroll
    for (int e = 0; e < 4; e++) {
      int idx = tid + e * 256;
      int k = idx >> 6, nn = idx & 63;
      Bs[k][nn] = w[(size_t)(C + kt + k) * O + n0 + nn];
    }
    __syncthreads();
#pragma unroll
    for (int kk = 0; kk < TK; kk++) {
      float4 a0 = *(const float4*)&As[kk][ty * 8];
      float4 a1 = *(const float4*)&As[kk][ty * 8 + 4];
      float4 b0 = *(const float4*)&Bs[kk][tx * 4];
      float av[8] = {a0.x, a0.y, a0.z, a0.w, a1.x, a1.y, a1.z, a1.w};
      float bb[4] = {b0.x, b0.y, b0.z, b0.w};
#pragma unroll
      for (int i = 0; i < 8; i++)
#pragma unroll
        for (int j = 0; j < 4; j++) acc[i][j] += av[i] * bb[j];
    }
    __syncthreads();
  }
#pragma unroll
  for (int i = 0; i < 8; i++)
#pragma unroll
    for (int j = 0; j < 4; j++)
      t0buf[(m0 + ty * 8 + i) * O + n0 + tx * 4 + j] = acc[i][j];
}

// ---------------------------------------------------------------------------
// weight -> bf16 hi/lo split in 16x16x32 B-fragment order.
// ---------------------------------------------------------------------------
template <int C, int O>
__global__ void k_wprep(const float* __restrict__ w,
                        unsigned short* __restrict__ whi,
                        unsigned short* __restrict__ wlo) {
  int e = blockIdx.x * 256 + threadIdx.x;
  if (e >= C * O) return;
  constexpr int NT = O / 16;
  int j = e & 7;
  int slot = e >> 3;
  int lane = slot & 63;
  int t2 = slot >> 6;
  int nt = t2 % NT, kb = t2 / NT;
  int k = kb * 32 + ((lane >> 4) & 3) * 8 + j;
  int n = nt * 16 + (lane & 15);
  float v = w[(size_t)k * O + n];
  unsigned short h = f2bf(v);
  unsigned short l = f2bf(v - bf2f(h));
  whi[e] = h;
  wlo[e] = l;
}

// ---------------------------------------------------------------------------
// feature matrix -> bf16 hi/lo split in 16x16x32 A-fragment order for mlp5.
// ---------------------------------------------------------------------------
__global__ void k_aprep(const float* __restrict__ x1, const float* __restrict__ x2,
                        const float* __restrict__ x3, const float* __restrict__ x4,
                        unsigned short* __restrict__ ah, unsigned short* __restrict__ al) {
  int e8 = blockIdx.x * 256 + threadIdx.x;
  if (e8 >= 16 * 1024 * 64) return;
  int lane = e8 & 63;
  int mtg = (e8 >> 6) & 1023;
  int kb = e8 >> 16;
  int m = mtg * 16 + (lane & 15);
  int k0 = kb * 32 + ((lane >> 4) & 3) * 8;
  const float* p;
  if (k0 < 64)       p = &x1[(size_t)m * 64 + k0];
  else if (k0 < 128) p = &x2[(size_t)m * 64 + (k0 - 64)];
  else if (k0 < 256) p = &x3[(size_t)m * 128 + (k0 - 128)];
  else               p = &x4[(size_t)m * 256 + (k0 - 256)];
  float4 f0 = *(const float4*)p;
  float4 f1 = *(const float4*)(p + 4);
  float fv[8] = {f0.x, f0.y, f0.z, f0.w, f1.x, f1.y, f1.z, f1.w};
  short8 h8, l8;
#pragma unroll
  for (int j = 0; j < 8; j++) {
    unsigned short h = f2bf(fv[j]);
    unsigned short l = f2bf(fv[j] - bf2f(h));
    h8[j] = (short)h;
    l8[j] = (short)l;
  }
  *(short8*)&ah[(size_t)e8 * 8] = h8;
  *(short8*)&al[(size_t)e8 * 8] = l8;
}

// ---------------------------------------------------------------------------
// MFMA edge conv (C in {64,128}): per block 2 points, 32 padded neighbor rows.
// Split bf16: D ~= AhBh + AhBl + AlBh.
// R16: staging restructured into flat phases (all indices -> all gathers ->
// convert/store). Pad rows gather the CENTER point: d = ctr - ctr = 0.0
// exactly (bit-identical to the old zero-fill) -> no branch, and all 16
// gathers sit in flight instead of serializing at 68 VGPRs.
// ---------------------------------------------------------------------------
template <int C, int O>
__global__ __launch_bounds__(256) void k_edge_mfma(
    const float* __restrict__ x, const int* __restrict__ knn,
    const unsigned short* __restrict__ whi, const unsigned short* __restrict__ wlo,
    const float* __restrict__ t0buf, const float* __restrict__ g,
    const float* __restrict__ bta, float* __restrict__ out) {
  constexpr int KB = C / 32;
  constexpr int NT = O / 16;
  constexpr int NTW = NT / 2;
  __shared__ unsigned short Ah[2 * 2 * KB * 512];
  __shared__ unsigned short Al[2 * 2 * KB * 512];

  const int blk = blockIdx.x;
  const int b = blk / (NPTS / 2);
  const int n0 = (blk % (NPTS / 2)) * 2;
  const int tid = threadIdx.x;
  const int lane = tid & 63;
  const int wid = tid >> 6;
  const int pt = wid >> 1;
  const int nsl = wid & 1;
  const int ptg = b * NPTS + n0 + pt;
  const float* xb = x + (size_t)b * NPTS * C;
  const int kbase = ptg * KNN;

  // phase 1: all neighbor indices (pad rows -> center; diff is exactly 0)
  int midx[16];
#pragma unroll
  for (int i = 0; i < 16; i++) {
    int r = 2 * i + nsl;
    midx[i] = (r < KNN) ? knn[kbase + r] : (n0 + pt);
  }

  if constexpr (C == 128) {
    const float2 ctr2 = *(const float2*)&xb[(size_t)(n0 + pt) * C + lane * 2];
    const int kb = lane >> 4;
    const int q = (lane >> 2) & 3;
    const int j2 = 2 * (lane & 3);
    // phase 2: all gathers in flight
    float2 vv[16];
#pragma unroll
    for (int i = 0; i < 16; i++)
      vv[i] = *(const float2*)&xb[(size_t)midx[i] * C + lane * 2];
    // phase 3: convert + swizzled LDS store
#pragma unroll
    for (int i = 0; i < 16; i++) {
      int r = 2 * i + nsl;
      float d0 = vv[i].x - ctr2.x, d1 = vv[i].y - ctr2.y;
      unsigned short h0 = f2bf(d0), h1 = f2bf(d1);
      unsigned short l0 = f2bf(d0 - bf2f(h0)), l1 = f2bf(d1 - bf2f(h1));
      unsigned hp = (unsigned)h0 | ((unsigned)h1 << 16);
      unsigned lp = (unsigned)l0 | ((unsigned)l1 << 16);
      int mt = r >> 4, row = r & 15;
      int L = row + 16 * q;
      int phys = L ^ ((4 * kb + q) & 15);
      int idx = ((pt * 2 + mt) * KB + kb) * 512 + phys * 8 + j2;
      *(unsigned*)&Ah[idx] = hp;
      *(unsigned*)&Al[idx] = lp;
    }
  } else {  // C == 64
    const float ctrv = xb[(size_t)(n0 + pt) * C + lane];
    const int kb = lane >> 5;
    const int q = (lane >> 3) & 3;
    const int j = lane & 7;
    float vv[16];
#pragma unroll
    for (int i = 0; i < 16; i++)
      vv[i] = xb[(size_t)midx[i] * C + lane];
#pragma unroll
    for (int i = 0; i < 16; i++) {
      int r = 2 * i + nsl;
      float d = vv[i] - ctrv;
      unsigned short h = f2bf(d);
      unsigned short l = f2bf(d - bf2f(h));
      int mt = r >> 4, row = r & 15;
      int L = row + 16 * q;
      int phys = L ^ ((4 * kb + q) & 15);
      int idx = ((pt * 2 + mt) * KB + kb) * 512 + phys * 8 + j;
      Ah[idx] = h;
      Al[idx] = l;
    }
  }
  __syncthreads();

  f32x4 acc[2][NTW];
#pragma unroll
  for (int mt = 0; mt < 2; mt++)
#pragma unroll
    for (int t = 0; t < NTW; t++) acc[mt][t] = (f32x4){0.f, 0.f, 0.f, 0.f};

#pragma unroll
  for (int kb = 0; kb < KB; kb++) {
    int phys = lane ^ ((4 * kb + (lane >> 4)) & 15);
    short8 ah[2], al[2];
#pragma unroll
    for (int mt = 0; mt < 2; mt++) {
      int idx = ((pt * 2 + mt) * KB + kb) * 512 + phys * 8;
      ah[mt] = *(const short8*)&Ah[idx];
      al[mt] = *(const short8*)&Al[idx];
    }
#pragma unroll
    for (int t = 0; t < NTW; t++) {
      int nt = nsl * NTW + t;
      size_t widx = ((size_t)(kb * NT + nt) * 64 + lane) * 8;
      short8 bh = *(const short8*)&whi[widx];
      short8 bl = *(const short8*)&wlo[widx];
#pragma unroll
      for (int mt = 0; mt < 2; mt++) {
        acc[mt][t] = __builtin_amdgcn_mfma_f32_16x16x32_bf16(ah[mt], bh, acc[mt][t], 0, 0, 0);
        acc[mt][t] = __builtin_amdgcn_mfma_f32_16x16x32_bf16(ah[mt], bl, acc[mt][t], 0, 0, 0);
        acc[mt][t] = __builtin_amdgcn_mfma_f32_16x16x32_bf16(al[mt], bh, acc[mt][t], 0, 0, 0);
      }
    }
  }

#pragma unroll
  for (int t = 0; t < NTW; t++) {
    int o = (nsl * NTW + t) * 16 + (lane & 15);
    float tv = t0buf[(size_t)ptg * O + o];
    float gv = g[o], bv = bta[o];
    float m = -3.0e38f;
#pragma unroll
    for (int mt = 0; mt < 2; mt++)
#pragma unroll
      for (int r = 0; r < 4; r++) {
        float h = (acc[mt][t][r] + tv) * gv + bv;
        h = (h >= 0.f) ? h : 0.2f * h;
        m = fmaxf(m, h);
      }
    m = fmaxf(m, __shfl_xor(m, 16));
    m = fmaxf(m, __shfl_xor(m, 32));
    if (lane < 16) out[(size_t)ptg * O + o] = m;
  }
}

// ---------------------------------------------------------------------------
// fp32 edge conv -- retained for conv1 (C=3) only.
// ---------------------------------------------------------------------------
template <int C, int O>
__global__ __launch_bounds__(256) void k_edge(const float* __restrict__ x,
                                              const int* __restrict__ knn,
                                              const float* __restrict__ w,
                                              const float* __restrict__ g,
                                              const float* __restrict__ bta,
                                              float* __restrict__ out) {
  constexpr int JO = O / 64;
  constexpr int NPB = 4;
  __shared__ __attribute__((aligned(16))) float nbd[NPB * KNN * C];

  const int blk = blockIdx.x;
  const int b = blk / (NPTS / NPB);
  const int n0 = (blk % (NPTS / NPB)) * NPB;
  const int tid = threadIdx.x;
  const int lane = tid & 63;
  const int p = tid >> 6;
  const float* xb = x + (size_t)b * NPTS * C;

  const int kbase = (b * NPTS + n0 + p) * KNN;
  float* nb_p = nbd + p * KNN * C;
  int midx[KNN];
#pragma unroll
  for (int k = 0; k < KNN; k++) midx[k] = knn[kbase + k];

  float cv0 = 0.f;
  if (lane < C) cv0 = xb[(size_t)(n0 + p) * C + lane];
  float vv[KNN];
#pragma unroll
  for (int k = 0; k < KNN; k++)
    vv[k] = (lane < C) ? xb[(size_t)midx[k] * C + lane] : 0.f;
#pragma unroll
  for (int k = 0; k < KNN; k++)
    if (lane < C) nb_p[k * C + lane] = vv[k] - cv0;

  float acc[KNN][JO];
  {
    float t0[JO];
#pragma unroll
    for (int j = 0; j < JO; j++) t0[j] = 0.f;
    for (int c = 0; c < C; c++) {
      float cc = __shfl(cv0, c);
#pragma unroll
      for (int j = 0; j < JO; j++)
        t0[j] += cc * w[(size_t)(C + c) * O + j * 64 + lane];
    }
#pragma unroll
    for (int k = 0; k < KNN; k++)
#pragma unroll
      for (int j = 0; j < JO; j++) acc[k][j] = t0[j];
  }

  for (int c = 0; c < C; c++) {
    float wv[JO];
#pragma unroll
    for (int j = 0; j < JO; j++) wv[j] = w[(size_t)c * O + j * 64 + lane];
#pragma unroll
    for (int k = 0; k < KNN; k++) {
      float f = nb_p[k * C + c];
#pragma unroll
      for (int j = 0; j < JO; j++) acc[k][j] += f * wv[j];
    }
  }

#pragma unroll
  for (int j = 0; j < JO; j++) {
    const float gv = g[j * 64 + lane], bv = bta[j * 64 + lane];
    float mx = -3.0e38f;
#pragma unroll
    for (int k = 0; k < KNN; k++) {
      float h = acc[k][j] * gv + bv;
      h = (h >= 0.f) ? h : 0.2f * h;
      mx = fmaxf(mx, h);
    }
    out[(size_t)(b * NPTS + n0 + p) * O + j * 64 + lane] = mx;
  }
}

// ---------------------------------------------------------------------------
// point MLP 512->1024 as split-bf16 MFMA GEMM, no LDS, no barriers.
// ---------------------------------------------------------------------------
__global__ __launch_bounds__(256) void k_mlp5(const unsigned short* __restrict__ a5h,
                                              const unsigned short* __restrict__ a5l,
                                              const unsigned short* __restrict__ w5h,
                                              const unsigned short* __restrict__ w5l,
                                              const float* __restrict__ g5,
                                              const float* __restrict__ b5,
                                              float* __restrict__ pmax,
                                              float* __restrict__ psum) {
  const int mtb = blockIdx.x;
  const int ntb = blockIdx.y;
  const int tid = threadIdx.x;
  const int lane = tid & 63;
  const int nsl = tid >> 6;

  f32x4 acc[8][2];
#pragma unroll
  for (int mt = 0; mt < 8; mt++)
#pragma unroll
    for (int t = 0; t < 2; t++) acc[mt][t] = (f32x4){0.f, 0.f, 0.f, 0.f};

  for (int kb = 0; kb < 16; kb++) {
    short8 bh[2], bl[2];
#pragma unroll
    for (int t = 0; t < 2; t++) {
      int ntg = ntb * 8 + nsl * 2 + t;
      size_t widx = ((size_t)(kb * 64 + ntg) * 64 + lane) * 8;
      bh[t] = *(const short8*)&w5h[widx];
      bl[t] = *(const short8*)&w5l[widx];
    }
#pragma unroll
    for (int mt = 0; mt < 8; mt++) {
      size_t aidx = (((size_t)kb * 1024 + mtb * 8 + mt) * 64 + lane) * 8;
      short8 ah = *(const short8*)&a5h[aidx];
      short8 al = *(const short8*)&a5l[aidx];
#pragma unroll
      for (int t = 0; t < 2; t++) {
        acc[mt][t] = __builtin_amdgcn_mfma_f32_16x16x32_bf16(ah, bh[t], acc[mt][t], 0, 0, 0);
        acc[mt][t] = __builtin_amdgcn_mfma_f32_16x16x32_bf16(ah, bl[t], acc[mt][t], 0, 0, 0);
        acc[mt][t] = __builtin_amdgcn_mfma_f32_16x16x32_bf16(al, bh[t], acc[mt][t], 0, 0, 0);
      }
    }
  }

#pragma unroll
  for (int t = 0; t < 2; t++) {
    int o = ntb * 128 + (nsl * 2 + t) * 16 + (lane & 15);
    float gv = g5[o], bv = b5[o];
    float mx = -3.0e38f, sm = 0.f;
#pragma unroll
    for (int mt = 0; mt < 8; mt++)
#pragma unroll
      for (int r = 0; r < 4; r++) {
        float h = acc[mt][t][r] * gv + bv;
        h = (h >= 0.f) ? h : 0.2f * h;
        mx = fmaxf(mx, h);
        sm += h;
      }
    mx = fmaxf(mx, __shfl_xor(mx, 16));
    mx = fmaxf(mx, __shfl_xor(mx, 32));
    sm += __shfl_xor(sm, 16);
    sm += __shfl_xor(sm, 32);
    if (lane < 16) {
      pmax[(size_t)mtb * 1024 + o] = mx;
      psum[(size_t)mtb * 1024 + o] = sm;
    }
  }
}

// ---------------------------------------------------------------------------
// reduce tile partials -> pooled (B, 2048) = [max(1024), mean(1024)]
// ---------------------------------------------------------------------------
__global__ void k_pool(const float* __restrict__ pmax, const float* __restrict__ psum,
                       float* __restrict__ pooled) {
  int i = blockIdx.x * 256 + threadIdx.x;
  if (i >= NBATCH * 1024) return;
  int b = i / 1024, e = i - b * 1024;
  constexpr int NT = NPTS / 128;
  float mx = -3.0e38f, sm = 0.f;
  for (int t = 0; t < NT; t++) {
    mx = fmaxf(mx, pmax[((size_t)b * NT + t) * 1024 + e]);
    sm += psum[((size_t)b * NT + t) * 1024 + e];
  }
  pooled[(size_t)b * 2048 + e] = mx;
  pooled[(size_t)b * 2048 + 1024 + e] = sm * (1.0f / NPTS);
}

// ---------------------------------------------------------------------------
// head layer 1: h1g[b,o] = leaky((pooled[b,:] @ wl1)[o] * g6[o] + b6[o]).
// grid (8 o-chunks, NBATCH); wave ks covers k-slice [ks*512,(ks+1)*512).
// ---------------------------------------------------------------------------
__global__ __launch_bounds__(256) void k_head1(const float* __restrict__ pooled,
                                               const float* __restrict__ wl1,
                                               const float* __restrict__ g6,
                                               const float* __restrict__ b6,
                                               float* __restrict__ h1g) {
  const int os = blockIdx.x;
  const int b = blockIdx.y;
  const int tid = threadIdx.x;
  const int lane = tid & 63;
  const int ks = tid >> 6;
  const int o = os * 64 + lane;
  __shared__ float pl[2048];
  __shared__ float part[4][64];

  for (int i = tid; i < 2048; i += 256) pl[i] = pooled[(size_t)b * 2048 + i];
  __syncthreads();

  float a = 0.f;
  const int c0 = ks * 512;
  for (int c = 0; c < 512; c++)
    a += pl[c0 + c] * wl1[(size_t)(c0 + c) * 512 + o];
  part[ks][lane] = a;
  __syncthreads();

  if (ks == 0) {
    float s = part[0][lane];
    s += part[1][lane];
    s += part[2][lane];
    s += part[3][lane];
    s = s * g6[o] + b6[o];
    h1g[(size_t)b * 512 + o] = (s >= 0.f) ? s : 0.2f * s;
  }
}

// ---------------------------------------------------------------------------
// head layers 2+3: 512 ->(bias,affine,leaky) 256 -> 40 (+bias).
// ---------------------------------------------------------------------------
__global__ __launch_bounds__(256) void k_head23(const float* __restrict__ h1g,
                                                const float* __restrict__ wl2,
                                                const float* __restrict__ bl2,
                                                const float* __restrict__ g7,
                                                const float* __restrict__ b7,
                                                const float* __restrict__ wl3,
                                                const float* __restrict__ bl3,
                                                float* __restrict__ out) {
  const int b = blockIdx.x;
  const int tid = threadIdx.x;
  __shared__ float h1[512];
  __shared__ float h2[256];

  for (int i = tid; i < 512; i += 256) h1[i] = h1g[(size_t)b * 512 + i];
  __syncthreads();

  {
    float a = 0.f;
    for (int c = 0; c < 512; c++) a += h1[c] * wl2[(size_t)c * 256 + tid];
    a = (a + bl2[tid]) * g7[tid] + b7[tid];
    h2[tid] = (a >= 0.f) ? a : 0.2f * a;
  }
  __syncthreads();

  if (tid < 40) {
    float a = bl3[tid];
    for (int c = 0; c < 256; c++) a += h2[c] * wl3[(size_t)c * 40 + tid];
    out[(size_t)b * 40 + tid] = a;
  }
}

// ---------------------------------------------------------------------------
extern "C" void kernel_launch(void* const* d_in, const int* in_sizes, int n_in,
                              void* d_out, int out_size, void* d_ws, size_t ws_size,
                              hipStream_t stream) {
  (void)in_sizes; (void)n_in; (void)out_size;
  const float* x   = (const float*)d_in[0];
  const float* w1  = (const float*)d_in[1];
  const float* g1  = (const float*)d_in[2];
  const float* b1  = (const float*)d_in[3];
  const float* w2  = (const float*)d_in[4];
  const float* g2  = (const float*)d_in[5];
  const float* b2  = (const float*)d_in[6];
  const float* w3  = (const float*)d_in[7];
  const float* g3  = (const float*)d_in[8];
  const float* b3  = (const float*)d_in[9];
  const float* w4  = (const float*)d_in[10];
  const float* g4  = (const float*)d_in[11];
  const float* b4  = (const float*)d_in[12];
  const float* w5  = (const float*)d_in[13];
  const float* g5  = (const float*)d_in[14];
  const float* b5  = (const float*)d_in[15];
  const float* wl1 = (const float*)d_in[16];
  const float* g6  = (const float*)d_in[17];
  const float* b6  = (const float*)d_in[18];
  const float* wl2 = (const float*)d_in[19];
  const float* bl2 = (const float*)d_in[20];
  const float* g7  = (const float*)d_in[21];
  const float* b7  = (const float*)d_in[22];
  const float* wl3 = (const float*)d_in[23];
  const float* bl3 = (const float*)d_in[24];

  float* ws = (float*)d_ws;
  size_t off = 0;
  float* h0 = ws + off;   off += (size_t)NBATCH * NPTS * 3;
  float* x1 = ws + off;   off += (size_t)NBATCH * NPTS * 64;
  float* x2 = ws + off;   off += (size_t)NBATCH * NPTS * 64;
  float* x3 = ws + off;   off += (size_t)NBATCH * NPTS * 128;
  float* x4 = ws + off;   off += (size_t)NBATCH * NPTS * 256;
  int* knn = (int*)(ws + off); off += (size_t)NBATCH * NPTS * KNN;
  float* pmax = ws + off; off += (size_t)(NPTS / 128) * NBATCH * 1024;
  float* psum = ws + off; off += (size_t)(NPTS / 128) * NBATCH * 1024;
  float* pooled = ws + off; off += (size_t)NBATCH * 2048;
  float* h1g = ws + off;  off += (size_t)NBATCH * 512;
  float* t0buf = ws + off;  off += (size_t)NBATCH * NPTS * 256;  // max O
  unsigned short* w2h = (unsigned short*)(ws + off); off += 64 * 64 / 2 * 2;
  unsigned short* w2l = w2h + 64 * 64;
  unsigned short* w3h = (unsigned short*)(ws + off); off += 64 * 128 / 2 * 2;
  unsigned short* w3l = w3h + 64 * 128;
  unsigned short* w4h = (unsigned short*)(ws + off); off += 128 * 256 / 2 * 2;
  unsigned short* w4l = w4h + 128 * 256;
  unsigned short* w5h = (unsigned short*)(ws + off); off += 512 * 1024 / 2 * 2;
  unsigned short* w5l = w5h + 512 * 1024;
  unsigned short* a5h = (unsigned short*)(ws + off); off += (size_t)16384 * 512 / 2 * 2;
  unsigned short* a5l = a5h + (size_t)16384 * 512;
  float* dist = ws + off;  // adaptive: nb_grp * NPTS * NPTS floats, placed last

  size_t avail = ws_size / 4 - off;
  int nb_grp = 8;
  while (nb_grp > 1 && (size_t)nb_grp * NPTS * NPTS > avail) nb_grp >>= 1;

  constexpr int NTRI = (NPTS / 64) * (NPTS / 64 + 1) / 2;  // 528

  k_transpose<<<(NBATCH * NPTS * 3 + 255) / 256, 256, 0, stream>>>(x, h0);

  // weight hi/lo fragment prep (depends only on inputs -- run up front)
  k_wprep<64, 64><<<(64 * 64 + 255) / 256, 256, 0, stream>>>(w2, w2h, w2l);
  k_wprep<64, 128><<<(64 * 128 + 255) / 256, 256, 0, stream>>>(w3, w3h, w3l);
  k_wprep<128, 256><<<(128 * 256 + 255) / 256, 256, 0, stream>>>(w4, w4h, w4l);
  k_wprep<512, 1024><<<(512 * 1024 + 255) / 256, 256, 0, stream>>>(w5, w5h, w5l);

  // ---- edge conv 1 (C=3 -> O=64): fused register kNN (wave/row) + fp32 edge
  k_knn3<<<dim3(NPTS / 4, NBATCH), 256, 0, stream>>>(h0, knn);
  k_edge<3, 64><<<NBATCH * NPTS / 4, 256, 0, stream>>>(h0, knn, w1, g1, b1, x1);

  // ---- edge conv 2 (C=64 -> O=64)
  for (int b0 = 0; b0 < NBATCH; b0 += nb_grp) {
    k_dist<64><<<dim3(NTRI, 1, nb_grp), 256, 0, stream>>>(
        x1 + (size_t)b0 * NPTS * 64, dist);
    k_topk<<<dim3(NPTS / 4, nb_grp), 256, 0, stream>>>(dist,
                                                       knn + (size_t)b0 * NPTS * KNN);
  }
  k_t0<64, 64><<<dim3(NBATCH * NPTS / 128, 1), 256, 0, stream>>>(x1, w2, t0buf);
  k_edge_mfma<64, 64><<<NBATCH * NPTS / 2, 256, 0, stream>>>(x1, knn, w2h, w2l, t0buf,
                                                             g2, b2, x2);

  // ---- edge conv 3 (C=64 -> O=128)
  for (int b0 = 0; b0 < NBATCH; b0 += nb_grp) {
    k_dist<64><<<dim3(NTRI, 1, nb_grp), 256, 0, stream>>>(
        x2 + (size_t)b0 * NPTS * 64, dist);
    k_topk<<<dim3(NPTS / 4, nb_grp), 256, 0, stream>>>(dist,
                                                       knn + (size_t)b0 * NPTS * KNN);
  }
  k_t0<64, 128><<<dim3(NBATCH * NPTS / 128, 2), 256, 0, stream>>>(x2, w3, t0buf);
  k_edge_mfma<64, 128><<<NBATCH * NPTS / 2, 256, 0, stream>>>(x2, knn, w3h, w3l, t0buf,
                                                              g3, b3, x3);

  // ---- edge conv 4 (C=128 -> O=256)
  for (int b0 = 0; b0 < NBATCH; b0 += nb_grp) {
    k_dist<128><<<dim3(NTRI, 1, nb_grp), 256, 0, stream>>>(
        x3 + (size_t)b0 * NPTS * 128, dist);
    k_topk<<<dim3(NPTS / 4, nb_grp), 256, 0, stream>>>(dist,
                                                       knn + (size_t)b0 * NPTS * KNN);
  }
  k_t0<128, 256><<<dim3(NBATCH * NPTS / 128, 4), 256, 0, stream>>>(x3, w4, t0buf);
  k_edge_mfma<128, 256><<<NBATCH * NPTS / 2, 256, 0, stream>>>(x3, knn, w4h, w4l, t0buf,
                                                               g4, b4, x4);

  // ---- point MLP (split-bf16 MFMA GEMM) + pooling + head
  k_aprep<<<(16 * 1024 * 64 + 255) / 256, 256, 0, stream>>>(x1, x2, x3, x4, a5h, a5l);
  k_mlp5<<<dim3(NBATCH * NPTS / 128, 8), 256, 0, stream>>>(a5h, a5l, w5h, w5l, g5, b5,
                                                           pmax, psum);
  k_pool<<<(NBATCH * 1024 + 255) / 256, 256, 0, stream>>>(pmax, psum, pooled);
  k_head1<<<dim3(8, NBATCH), 256, 0, stream>>>(pooled, wl1, g6, b6, h1g);
  k_head23<<<NBATCH, 256, 0, stream>>>(h1g, wl2, bl2, g7, b7, wl3, bl3,
                                       (float*)d_out);
}

// Round 3
// 674.665 us; speedup vs baseline: 1.5197x; 1.1788x over previous
//
#include <hip/hip_runtime.h>
#include <cstddef>
#include <cstdint>

#define NBATCH 8
#define NPTS   2048
#define KNN    20

typedef __attribute__((ext_vector_type(8))) short short8;
typedef __attribute__((ext_vector_type(4))) float f32x4;

__device__ __forceinline__ unsigned short f2bf(float f) {
  unsigned u = __float_as_uint(f);
  u += 0x7fff + ((u >> 16) & 1);   // round-to-nearest-even
  return (unsigned short)(u >> 16);
}
__device__ __forceinline__ float bf2f(unsigned short h) {
  return __uint_as_float(((unsigned)h) << 16);
}

// monotone float -> orderable uint (ascending uint == ascending float)
__device__ __forceinline__ unsigned f2ord(float f) {
  unsigned u = __float_as_uint(f);
  return (u & 0x80000000u) ? ~u : (u | 0x80000000u);
}

// ---------------------------------------------------------------------------
// 64-lane bitonic sort, ascending across lanes. 21 compare-exchange stages.
// ---------------------------------------------------------------------------
template <typename T>
__device__ __forceinline__ T bitonic_sort_asc(T key, int lane) {
#pragma unroll
  for (int k = 2; k <= 64; k <<= 1) {
#pragma unroll
    for (int j = k >> 1; j > 0; j >>= 1) {
      T other = __shfl_xor(key, j);
      bool takemax = ((lane & k) == 0) != ((lane & j) == 0);
      key = takemax ? (key > other ? key : other)
                    : (key < other ? key : other);
    }
  }
  return key;
}

// ---------------------------------------------------------------------------
// exact serial fallback (ord-space port of the R15 top-2-cache extractor).
// Only taken when >64 values tie above the threshold -- effectively never.
// ---------------------------------------------------------------------------
__device__ void wave_top20_serial(const unsigned (&v)[32], int lane,
                                  int* __restrict__ row_out) {
  unsigned m1 = 0, m2 = 0;
  int i1 = 0, i2 = 0;
#pragma unroll
  for (int i = 0; i < 32; i++) {
    unsigned x = v[i];
    if (x > m1) { m2 = m1; i2 = i1; m1 = x; i1 = i; }
    else if (x > m2) { m2 = x; i2 = i; }
  }

  unsigned dm = 0;
  int cnt = 2;
  int keep = 0;
  for (int k = 0; k < KNN; k++) {
    unsigned rv = m1;
    int ri = i1 * 64 + lane;
#pragma unroll
    for (int off = 32; off > 0; off >>= 1) {
      unsigned ov = __shfl_down(rv, off);
      int oi = __shfl_down(ri, off);
      if (ov > rv || (ov == rv && oi < ri)) { rv = ov; ri = oi; }
    }
    int wi = __shfl(ri, 0);
    if (lane == k) keep = wi;
    if ((wi & 63) == lane) {
      dm |= 1u << (wi >> 6);
      if (cnt == 2) {
        m1 = m2; i1 = i2; cnt = 1;
      } else {
        m1 = 0; i1 = 0; m2 = 0; i2 = 0;
#pragma unroll
        for (int i = 0; i < 32; i++)
          if (!((dm >> i) & 1)) {
            unsigned x = v[i];
            if (x > m1) { m2 = m1; i2 = i1; m1 = x; i1 = i; }
            else if (x > m2) { m2 = x; i2 = i; }
          }
        cnt = 2;
      }
    }
  }
  if (lane < KNN) row_out[lane] = keep;
}

// ---------------------------------------------------------------------------
// wave-level exact top-20 over 2048 candidates (ord space): lane holds 32
// values, global index of v[i] on lane l is i*64 + l. One wave per row.
// R17: threshold (20th-largest lane max) -> ballot-compact candidates into
// LDS -> one 64-lane bitonic sort of packed (value, ~index) keys emits the
// top-20 in order with the lowest-index tie-break.
// ---------------------------------------------------------------------------
__device__ __forceinline__ void wave_top20(const unsigned (&v)[32], int lane,
                                           unsigned long long* cand,
                                           int* __restrict__ row_out) {
  // 1. per-lane max
  unsigned mo = 0;
#pragma unroll
  for (int i = 0; i < 32; i++) mo = (v[i] > mo) ? v[i] : mo;

  // 2. sort the 64 lane maxima; T = 20th largest (ascending lane 44).
  unsigned ms = bitonic_sort_asc(mo, lane);
  unsigned T = __shfl(ms, 64 - KNN);

  // 3. ballot-compact all values >= T into LDS.
  cand[lane] = 0ull;
  int base = 0;
#pragma unroll
  for (int i = 0; i < 32; i++) {
    bool p = v[i] >= T;
    unsigned long long mk = __ballot(p);
    if (p) {
      int pos = base + __popcll(mk & ((1ull << lane) - 1ull));
      if (pos < 64)
        cand[pos] = ((unsigned long long)v[i] << 32) |
                    (unsigned)(~(unsigned)(i * 64 + lane));
    }
    base += (int)__popcll(mk);
  }

  if (base <= 64) {
    // 4. one bitonic sort of packed keys; key = (ord << 32) | ~idx.
    unsigned long long key = cand[lane];
    key = bitonic_sort_asc(key, lane);
    if (lane >= 64 - KNN)
      row_out[63 - lane] = (int)(~(unsigned)key);
  } else {
    wave_top20_serial(v, lane, row_out);
  }
}

// ---------------------------------------------------------------------------
// transpose (B,3,N) -> (B,N,3)
// ---------------------------------------------------------------------------
__global__ void k_transpose(const float* __restrict__ x, float* __restrict__ h0) {
  int i = blockIdx.x * 256 + threadIdx.x;
  if (i >= NBATCH * NPTS * 3) return;
  int c = i % 3;
  int n = (i / 3) % NPTS;
  int b = i / (3 * NPTS);
  h0[i] = x[((size_t)b * 3 + c) * NPTS + n];
}

// ---------------------------------------------------------------------------
// pairwise "distance" pd = 2*dot - sq_n - sq_m. blockIdx.z = batch in group.
// R11-proven 64x64 tile / 4x4 microtile, upper-triangular grid (528 blocks);
// off-diagonal blocks mirror their tile via an LDS bounce (bit-identical).
// ---------------------------------------------------------------------------
template <int C>
__global__ __launch_bounds__(256) void k_dist(const float* __restrict__ xg,
                                              float* __restrict__ dist) {
  constexpr int PAD = 4;
  constexpr int S = C + PAD;
  constexpr int TS = 67;
  __shared__ __attribute__((aligned(16))) float rows[64 * S];
  __shared__ __attribute__((aligned(16))) float cols[64 * S];
  __shared__ float sq[128];

  const float* xb = xg + (size_t)blockIdx.z * NPTS * C;
  float* db = dist + (size_t)blockIdx.z * NPTS * NPTS;

  constexpr int T = NPTS / 64;
  int bid = blockIdx.x;
  int rt = 0;
  while (bid >= T - rt) { bid -= T - rt; rt++; }
  const int ct = rt + bid;

  const int tid = threadIdx.x;

  for (int e = tid; e < 64 * C; e += 256) {
    int i = e / C, c = e - i * C;
    rows[i * S + c] = xb[(size_t)(rt * 64 + i) * C + c];
    cols[i * S + c] = xb[(size_t)(ct * 64 + i) * C + c];
  }
  __syncthreads();
  if (tid < 128) {
    const float* p = (tid < 64) ? (rows + tid * S) : (cols + (tid - 64) * S);
    float s = 0.f;
    for (int c = 0; c < C; c++) s += p[c] * p[c];
    sq[tid] = s;
  }
  __syncthreads();

  const int r0 = (tid >> 4) * 4;
  const int c0 = tid & 15;
  float acc[4][4] = {};

  for (int c = 0; c < C; c += 4) {
    float4 ra[4], cb[4];
#pragma unroll
    for (int i = 0; i < 4; i++) ra[i] = *(const float4*)&rows[(r0 + i) * S + c];
#pragma unroll
    for (int j = 0; j < 4; j++) cb[j] = *(const float4*)&cols[(c0 + 16 * j) * S + c];
#pragma unroll
    for (int i = 0; i < 4; i++)
#pragma unroll
      for (int j = 0; j < 4; j++)
        acc[i][j] += ra[i].x * cb[j].x + ra[i].y * cb[j].y +
                     ra[i].z * cb[j].z + ra[i].w * cb[j].w;
  }

  float pd[4][4];
#pragma unroll
  for (int i = 0; i < 4; i++) {
    float sr = sq[r0 + i];
#pragma unroll
    for (int j = 0; j < 4; j++)
      pd[i][j] = 2.f * acc[i][j] - sr - sq[64 + c0 + 16 * j];
  }

#pragma unroll
  for (int i = 0; i < 4; i++)
#pragma unroll
    for (int j = 0; j < 4; j++)
      db[(size_t)(rt * 64 + r0 + i) * NPTS + ct * 64 + c0 + 16 * j] = pd[i][j];

  if (rt != ct) {
    __syncthreads();
    float* tb = rows;
#pragma unroll
    for (int i = 0; i < 4; i++)
#pragma unroll
      for (int j = 0; j < 4; j++)
        tb[(c0 + 16 * j) * TS + r0 + i] = pd[i][j];
    __syncthreads();
#pragma unroll
    for (int i = 0; i < 4; i++)
#pragma unroll
      for (int j = 0; j < 4; j++)
        db[(size_t)(ct * 64 + r0 + i) * NPTS + rt * 64 + c0 + 16 * j] =
            tb[(r0 + i) * TS + c0 + 16 * j];
  }
}

// ---------------------------------------------------------------------------
// top-20 per row from materialized dist. One wave per row, 4 rows per block.
// ---------------------------------------------------------------------------
__global__ __launch_bounds__(256) void k_topk(const float* __restrict__ dist,
                                              int* __restrict__ idx_out) {
  __shared__ unsigned long long cand[4][64];
  const int wid = threadIdx.x >> 6;
  const int lane = threadIdx.x & 63;
  const int n = blockIdx.x * 4 + wid;
  const int z = blockIdx.y;
  const float* drow = dist + ((size_t)z * NPTS + n) * NPTS;
  int* row_out = idx_out + ((size_t)z * NPTS + n) * KNN;

  unsigned v[32];
#pragma unroll
  for (int i = 0; i < 32; i++) v[i] = f2ord(drow[i * 64 + lane]);

  wave_top20(v, lane, cand[wid], row_out);
}

// ---------------------------------------------------------------------------
// conv1 fused kNN (C=3): one wave per row, register recompute + wave_top20.
// ---------------------------------------------------------------------------
__global__ __launch_bounds__(256) void k_knn3(const float* __restrict__ x,
                                              int* __restrict__ idx_out) {
  __shared__ unsigned long long cand[4][64];
  const int wid = threadIdx.x >> 6;
  const int lane = threadIdx.x & 63;
  const int n = blockIdx.x * 4 + wid;
  const int b = blockIdx.y;
  const float* xb = x + (size_t)b * NPTS * 3;
  int* row_out = idx_out + ((size_t)b * NPTS + n) * KNN;

  const float qx = xb[n * 3 + 0], qy = xb[n * 3 + 1], qz = xb[n * 3 + 2];
  float qsq = 0.f;
  qsq += qx * qx; qsq += qy * qy; qsq += qz * qz;

  unsigned v[32];
#pragma unroll
  for (int i = 0; i < 32; i++) {
    int m = i * 64 + lane;
    float cx = xb[m * 3 + 0], cy = xb[m * 3 + 1], cz = xb[m * 3 + 2];
    float csq = 0.f;
    csq += cx * cx; csq += cy * cy; csq += cz * cz;
    float acc = 0.f;
    acc += qx * cx; acc += qy * cy; acc += qz * cz;
    v[i] = f2ord(2.f * acc - qsq - csq);
  }

  wave_top20(v, lane, cand[wid], row_out);
}

// ---------------------------------------------------------------------------
// dense GEMM: out[n, o] = sum_c x[n, c] * wpart[c, o]
// wpart points at the desired row-slice of w (w for the (nb-ctr) part,
// w + C*O for the ctr part). R18: the edge conv is linear in the gathered
// rows, so gather commutes with the GEMM -- these two dense GEMMs + a
// gather-max epilogue replace the whole padded-MFMA edge kernel.
// ---------------------------------------------------------------------------
template <int C, int O>
__global__ __launch_bounds__(256) void k_t0(const float* __restrict__ x,
                                            const float* __restrict__ wpart,
                                            float* __restrict__ outb) {
  constexpr int TM = 128, TN = 64, TK = 16;
  __shared__ __attribute__((aligned(16))) float As[TK][TM + 4];
  __shared__ __attribute__((aligned(16))) float Bs[TK][TN + 4];
  const int mt = blockIdx.x, nt = blockIdx.y;
  const int tid = threadIdx.x;
  const int tx = tid & 15, ty = tid >> 4;
  const size_t m0 = (size_t)mt * TM;
  const int n0 = nt * TN;
  float acc[8][4] = {};

  for (int kt = 0; kt < C; kt += TK) {
#pragma unroll
    for (int e = 0; e < 8; e++) {
      int idx = tid + e * 256;
      int m = idx >> 4, k = idx & 15;
      As[k][m] = x[(m0 + m) * C + kt + k];
    }
#pragma unroll
    for (int e = 0; e < 4; e++) {
      int idx = tid + e * 256;
      int k = idx >> 6, nn = idx & 63;
      Bs[k][nn] = wpart[(size_t)(kt + k) * O + n0 + nn];
    }
    __syncthreads();
#pragma unroll
    for (int kk = 0; kk < TK; kk++) {
      float4 a0 = *(const float4*)&As[kk][ty * 8];
      float4 a1 = *(const float4*)&As[kk][ty * 8 + 4];
      float4 b0 = *(const float4*)&Bs[kk][tx * 4];
      float av[8] = {a0.x, a0.y, a0.z, a0.w, a1.x, a1.y, a1.z, a1.w};
      float bb[4] = {b0.x, b0.y, b0.z, b0.w};
#pragma unroll
      for (int i = 0; i < 8; i++)
#pragma unroll
        for (int j = 0; j < 4; j++) acc[i][j] += av[i] * bb[j];
    }
    __syncthreads();
  }
#pragma unroll
  for (int i = 0; i < 8; i++)
#pragma unroll
    for (int j = 0; j < 4; j++)
      outb[(m0 + ty * 8 + i) * O + n0 + tx * 4 + j] = acc[i][j];
}

// ---------------------------------------------------------------------------
// conv1 tiny GEMM (C=3, O=64): one thread per (n,o), computes both the
// (nb-ctr) part y and the ctr part t0 in one pass.
// ---------------------------------------------------------------------------
__global__ void k_t3(const float* __restrict__ x, const float* __restrict__ w,
                     float* __restrict__ y, float* __restrict__ t0) {
  int i = blockIdx.x * 256 + threadIdx.x;
  if (i >= NBATCH * NPTS * 64) return;
  int o = i & 63;
  int n = i >> 6;
  float x0 = x[n * 3 + 0], x1v = x[n * 3 + 1], x2v = x[n * 3 + 2];
  y[i]  = x0 * w[0 * 64 + o] + x1v * w[1 * 64 + o] + x2v * w[2 * 64 + o];
  t0[i] = x0 * w[3 * 64 + o] + x1v * w[4 * 64 + o] + x2v * w[5 * 64 + o];
}

// ---------------------------------------------------------------------------
// edge conv epilogue: out[n,o] = max_k leaky((y[m_k,o] - y[n,o] + t0[n,o])
//                                            * g[o] + b[o]).
// Pure gather-max: no GEMM, no padding, no LDS, no barriers. float4 per
// lane, coalesced row gathers (rows are O*4 B contiguous, L2/L3-resident).
// grid MUST be NBATCH*NPTS/PPB (R19 fix: the O=64 calls were 4x over).
// ---------------------------------------------------------------------------
template <int O>
__global__ __launch_bounds__(256) void k_egather(
    const float* __restrict__ y, const float* __restrict__ t0,
    const int* __restrict__ knn, const float* __restrict__ g,
    const float* __restrict__ bta, float* __restrict__ out) {
  constexpr int TPP = O / 4;              // threads per point
  constexpr int PPB = 256 / TPP;          // points per block
  const int tid = threadIdx.x;
  const int pl = tid / TPP;
  const int oc = (tid % TPP) * 4;
  const int ptg = blockIdx.x * PPB + pl;  // global point index (b*NPTS+n)
  if (ptg >= NBATCH * NPTS) return;
  const int bb = ptg >> 11;               // NPTS = 2048
  const int* kp = knn + (size_t)ptg * KNN;
  const float* yb = y + (size_t)bb * NPTS * O;

  const float4 yc = *(const float4*)&y[(size_t)ptg * O + oc];
  const float4 tc = *(const float4*)&t0[(size_t)ptg * O + oc];
  const float4 gv = *(const float4*)&g[oc];
  const float4 bv = *(const float4*)&bta[oc];
  const float cx = tc.x - yc.x, cy = tc.y - yc.y;
  const float cz = tc.z - yc.z, cw = tc.w - yc.w;

  int midx[KNN];
#pragma unroll
  for (int k = 0; k < KNN; k++) midx[k] = kp[k];

  float4 vv[KNN];
#pragma unroll
  for (int k = 0; k < KNN; k++)
    vv[k] = *(const float4*)&yb[(size_t)midx[k] * O + oc];

  float m0 = -3.0e38f, m1 = -3.0e38f, m2 = -3.0e38f, m3 = -3.0e38f;
#pragma unroll
  for (int k = 0; k < KNN; k++) {
    float h0 = (vv[k].x + cx) * gv.x + bv.x;
    float h1 = (vv[k].y + cy) * gv.y + bv.y;
    float h2 = (vv[k].z + cz) * gv.z + bv.z;
    float h3 = (vv[k].w + cw) * gv.w + bv.w;
    h0 = (h0 >= 0.f) ? h0 : 0.2f * h0;
    h1 = (h1 >= 0.f) ? h1 : 0.2f * h1;
    h2 = (h2 >= 0.f) ? h2 : 0.2f * h2;
    h3 = (h3 >= 0.f) ? h3 : 0.2f * h3;
    m0 = fmaxf(m0, h0);
    m1 = fmaxf(m1, h1);
    m2 = fmaxf(m2, h2);
    m3 = fmaxf(m3, h3);
  }
  float4 res = {m0, m1, m2, m3};
  *(float4*)&out[(size_t)ptg * O + oc] = res;
}

// ---------------------------------------------------------------------------
// weight -> bf16 hi/lo split in 16x16x32 B-fragment order (mlp5 only).
// ---------------------------------------------------------------------------
template <int C, int O>
__global__ void k_wprep(const float* __restrict__ w,
                        unsigned short* __restrict__ whi,
                        unsigned short* __restrict__ wlo) {
  int e = blockIdx.x * 256 + threadIdx.x;
  if (e >= C * O) return;
  constexpr int NT = O / 16;
  int j = e & 7;
  int slot = e >> 3;
  int lane = slot & 63;
  int t2 = slot >> 6;
  int nt = t2 % NT, kb = t2 / NT;
  int k = kb * 32 + ((lane >> 4) & 3) * 8 + j;
  int n = nt * 16 + (lane & 15);
  float v = w[(size_t)k * O + n];
  unsigned short h = f2bf(v);
  unsigned short l = f2bf(v - bf2f(h));
  whi[e] = h;
  wlo[e] = l;
}

// ---------------------------------------------------------------------------
// feature matrix -> bf16 hi/lo split in 16x16x32 A-fragment order for mlp5.
// ---------------------------------------------------------------------------
__global__ void k_aprep(const float* __restrict__ x1, const float* __restrict__ x2,
                        const float* __restrict__ x3, const float* __restrict__ x4,
                        unsigned short* __restrict__ ah, unsigned short* __restrict__ al) {
  int e8 = blockIdx.x * 256 + threadIdx.x;
  if (e8 >= 16 * 1024 * 64) return;
  int lane = e8 & 63;
  int mtg = (e8 >> 6) & 1023;
  int kb = e8 >> 16;
  int m = mtg * 16 + (lane & 15);
  int k0 = kb * 32 + ((lane >> 4) & 3) * 8;
  const float* p;
  if (k0 < 64)       p = &x1[(size_t)m * 64 + k0];
  else if (k0 < 128) p = &x2[(size_t)m * 64 + (k0 - 64)];
  else if (k0 < 256) p = &x3[(size_t)m * 128 + (k0 - 128)];
  else               p = &x4[(size_t)m * 256 + (k0 - 256)];
  float4 f0 = *(const float4*)p;
  float4 f1 = *(const float4*)(p + 4);
  float fv[8] = {f0.x, f0.y, f0.z, f0.w, f1.x, f1.y, f1.z, f1.w};
  short8 h8, l8;
#pragma unroll
  for (int j = 0; j < 8; j++) {
    unsigned short h = f2bf(fv[j]);
    unsigned short l = f2bf(fv[j] - bf2f(h));
    h8[j] = (short)h;
    l8[j] = (short)l;
  }
  *(short8*)&ah[(size_t)e8 * 8] = h8;
  *(short8*)&al[(size_t)e8 * 8] = l8;
}

// ---------------------------------------------------------------------------
// point MLP 512->1024 as split-bf16 MFMA GEMM, no LDS, no barriers.
// ---------------------------------------------------------------------------
__global__ __launch_bounds__(256) void k_mlp5(const unsigned short* __restrict__ a5h,
                                              const unsigned short* __restrict__ a5l,
                                              const unsigned short* __restrict__ w5h,
                                              const unsigned short* __restrict__ w5l,
                                              const float* __restrict__ g5,
                                              const float* __restrict__ b5,
                                              float* __restrict__ pmax,
                                              float* __restrict__ psum) {
  const int mtb = blockIdx.x;
  const int ntb = blockIdx.y;
  const int tid = threadIdx.x;
  const int lane = tid & 63;
  const int nsl = tid >> 6;

  f32x4 acc[8][2];
#pragma unroll
  for (int mt = 0; mt < 8; mt++)
#pragma unroll
    for (int t = 0; t < 2; t++) acc[mt][t] = (f32x4){0.f, 0.f, 0.f, 0.f};

  for (int kb = 0; kb < 16; kb++) {
    short8 bh[2], bl[2];
#pragma unroll
    for (int t = 0; t < 2; t++) {
      int ntg = ntb * 8 + nsl * 2 + t;
      size_t widx = ((size_t)(kb * 64 + ntg) * 64 + lane) * 8;
      bh[t] = *(const short8*)&w5h[widx];
      bl[t] = *(const short8*)&w5l[widx];
    }
#pragma unroll
    for (int mt = 0; mt < 8; mt++) {
      size_t aidx = (((size_t)kb * 1024 + mtb * 8 + mt) * 64 + lane) * 8;
      short8 ah = *(const short8*)&a5h[aidx];
      short8 al = *(const short8*)&a5l[aidx];
#pragma unroll
      for (int t = 0; t < 2; t++) {
        acc[mt][t] = __builtin_amdgcn_mfma_f32_16x16x32_bf16(ah, bh[t], acc[mt][t], 0, 0, 0);
        acc[mt][t] = __builtin_amdgcn_mfma_f32_16x16x32_bf16(ah, bl[t], acc[mt][t], 0, 0, 0);
        acc[mt][t] = __builtin_amdgcn_mfma_f32_16x16x32_bf16(al, bh[t], acc[mt][t], 0, 0, 0);
      }
    }
  }

#pragma unroll
  for (int t = 0; t < 2; t++) {
    int o = ntb * 128 + (nsl * 2 + t) * 16 + (lane & 15);
    float gv = g5[o], bv = b5[o];
    float mx = -3.0e38f, sm = 0.f;
#pragma unroll
    for (int mt = 0; mt < 8; mt++)
#pragma unroll
      for (int r = 0; r < 4; r++) {
        float h = acc[mt][t][r] * gv + bv;
        h = (h >= 0.f) ? h : 0.2f * h;
        mx = fmaxf(mx, h);
        sm += h;
      }
    mx = fmaxf(mx, __shfl_xor(mx, 16));
    mx = fmaxf(mx, __shfl_xor(mx, 32));
    sm += __shfl_xor(sm, 16);
    sm += __shfl_xor(sm, 32);
    if (lane < 16) {
      pmax[(size_t)mtb * 1024 + o] = mx;
      psum[(size_t)mtb * 1024 + o] = sm;
    }
  }
}

// ---------------------------------------------------------------------------
// reduce tile partials -> pooled (B, 2048) = [max(1024), mean(1024)]
// ---------------------------------------------------------------------------
__global__ void k_pool(const float* __restrict__ pmax, const float* __restrict__ psum,
                       float* __restrict__ pooled) {
  int i = blockIdx.x * 256 + threadIdx.x;
  if (i >= NBATCH * 1024) return;
  int b = i / 1024, e = i - b * 1024;
  constexpr int NT = NPTS / 128;
  float mx = -3.0e38f, sm = 0.f;
  for (int t = 0; t < NT; t++) {
    mx = fmaxf(mx, pmax[((size_t)b * NT + t) * 1024 + e]);
    sm += psum[((size_t)b * NT + t) * 1024 + e];
  }
  pooled[(size_t)b * 2048 + e] = mx;
  pooled[(size_t)b * 2048 + 1024 + e] = sm * (1.0f / NPTS);
}

// ---------------------------------------------------------------------------
// head layer 1: h1g[b,o] = leaky((pooled[b,:] @ wl1)[o] * g6[o] + b6[o]).
// ---------------------------------------------------------------------------
__global__ __launch_bounds__(256) void k_head1(const float* __restrict__ pooled,
                                               const float* __restrict__ wl1,
                                               const float* __restrict__ g6,
                                               const float* __restrict__ b6,
                                               float* __restrict__ h1g) {
  const int os = blockIdx.x;
  const int b = blockIdx.y;
  const int tid = threadIdx.x;
  const int lane = tid & 63;
  const int ks = tid >> 6;
  const int o = os * 64 + lane;
  __shared__ float pl[2048];
  __shared__ float part[4][64];

  for (int i = tid; i < 2048; i += 256) pl[i] = pooled[(size_t)b * 2048 + i];
  __syncthreads();

  float a = 0.f;
  const int c0 = ks * 512;
  for (int c = 0; c < 512; c++)
    a += pl[c0 + c] * wl1[(size_t)(c0 + c) * 512 + o];
  part[ks][lane] = a;
  __syncthreads();

  if (ks == 0) {
    float s = part[0][lane];
    s += part[1][lane];
    s += part[2][lane];
    s += part[3][lane];
    s = s * g6[o] + b6[o];
    h1g[(size_t)b * 512 + o] = (s >= 0.f) ? s : 0.2f * s;
  }
}

// ---------------------------------------------------------------------------
// head layers 2+3: 512 ->(bias,affine,leaky) 256 -> 40 (+bias).
// ---------------------------------------------------------------------------
__global__ __launch_bounds__(256) void k_head23(const float* __restrict__ h1g,
                                                const float* __restrict__ wl2,
                                                const float* __restrict__ bl2,
                                                const float* __restrict__ g7,
                                                const float* __restrict__ b7,
                                                const float* __restrict__ wl3,
                                                const float* __restrict__ bl3,
                                                float* __restrict__ out) {
  const int b = blockIdx.x;
  const int tid = threadIdx.x;
  __shared__ float h1[512];
  __shared__ float h2[256];

  for (int i = tid; i < 512; i += 256) h1[i] = h1g[(size_t)b * 512 + i];
  __syncthreads();

  {
    float a = 0.f;
    for (int c = 0; c < 512; c++) a += h1[c] * wl2[(size_t)c * 256 + tid];
    a = (a + bl2[tid]) * g7[tid] + b7[tid];
    h2[tid] = (a >= 0.f) ? a : 0.2f * a;
  }
  __syncthreads();

  if (tid < 40) {
    float a = bl3[tid];
    for (int c = 0; c < 256; c++) a += h2[c] * wl3[(size_t)c * 40 + tid];
    out[(size_t)b * 40 + tid] = a;
  }
}

// ---------------------------------------------------------------------------
extern "C" void kernel_launch(void* const* d_in, const int* in_sizes, int n_in,
                              void* d_out, int out_size, void* d_ws, size_t ws_size,
                              hipStream_t stream) {
  (void)in_sizes; (void)n_in; (void)out_size;
  const float* x   = (const float*)d_in[0];
  const float* w1  = (const float*)d_in[1];
  const float* g1  = (const float*)d_in[2];
  const float* b1  = (const float*)d_in[3];
  const float* w2  = (const float*)d_in[4];
  const float* g2  = (const float*)d_in[5];
  const float* b2  = (const float*)d_in[6];
  const float* w3  = (const float*)d_in[7];
  const float* g3  = (const float*)d_in[8];
  const float* b3  = (const float*)d_in[9];
  const float* w4  = (const float*)d_in[10];
  const float* g4  = (const float*)d_in[11];
  const float* b4  = (const float*)d_in[12];
  const float* w5  = (const float*)d_in[13];
  const float* g5  = (const float*)d_in[14];
  const float* b5  = (const float*)d_in[15];
  const float* wl1 = (const float*)d_in[16];
  const float* g6  = (const float*)d_in[17];
  const float* b6  = (const float*)d_in[18];
  const float* wl2 = (const float*)d_in[19];
  const float* bl2 = (const float*)d_in[20];
  const float* g7  = (const float*)d_in[21];
  const float* b7  = (const float*)d_in[22];
  const float* wl3 = (const float*)d_in[23];
  const float* bl3 = (const float*)d_in[24];

  float* ws = (float*)d_ws;
  size_t off = 0;
  float* h0 = ws + off;   off += (size_t)NBATCH * NPTS * 3;
  float* x1 = ws + off;   off += (size_t)NBATCH * NPTS * 64;
  float* x2 = ws + off;   off += (size_t)NBATCH * NPTS * 64;
  float* x3 = ws + off;   off += (size_t)NBATCH * NPTS * 128;
  float* x4 = ws + off;   off += (size_t)NBATCH * NPTS * 256;
  int* knn = (int*)(ws + off); off += (size_t)NBATCH * NPTS * KNN;
  float* pmax = ws + off; off += (size_t)(NPTS / 128) * NBATCH * 1024;
  float* psum = ws + off; off += (size_t)(NPTS / 128) * NBATCH * 1024;
  float* pooled = ws + off; off += (size_t)NBATCH * 2048;
  float* h1g = ws + off;  off += (size_t)NBATCH * 512;
  float* t0buf = ws + off;  off += (size_t)NBATCH * NPTS * 256;  // max O
  unsigned short* w5h = (unsigned short*)(ws + off); off += 512 * 1024 / 2 * 2;
  unsigned short* w5l = w5h + 512 * 1024;
  unsigned short* a5h = (unsigned short*)(ws + off); off += (size_t)16384 * 512 / 2 * 2;
  unsigned short* a5l = a5h + (size_t)16384 * 512;
  float* dist = ws + off;  // adaptive: nb_grp * NPTS * NPTS floats, placed last

  // ybuf (max NBATCH*NPTS*256 floats) aliases the a5h/a5l region: it is dead
  // before k_aprep writes a5h (stream-serial), and the region is 2x larger.
  float* ybuf = (float*)a5h;

  size_t avail = ws_size / 4 - off;
  int nb_grp = 8;
  while (nb_grp > 1 && (size_t)nb_grp * NPTS * NPTS > avail) nb_grp >>= 1;

  constexpr int NTRI = (NPTS / 64) * (NPTS / 64 + 1) / 2;  // 528

  k_transpose<<<(NBATCH * NPTS * 3 + 255) / 256, 256, 0, stream>>>(x, h0);

  // mlp5 weight hi/lo fragment prep (depends only on inputs -- run up front)
  k_wprep<512, 1024><<<(512 * 1024 + 255) / 256, 256, 0, stream>>>(w5, w5h, w5l);

  // ---- edge conv 1 (C=3 -> O=64): fused register kNN + GEMM-gather
  k_knn3<<<dim3(NPTS / 4, NBATCH), 256, 0, stream>>>(h0, knn);
  k_t3<<<(NBATCH * NPTS * 64 + 255) / 256, 256, 0, stream>>>(h0, w1, ybuf, t0buf);
  k_egather<64><<<NBATCH * NPTS / 16, 256, 0, stream>>>(ybuf, t0buf, knn, g1, b1, x1);

  // ---- edge conv 2 (C=64 -> O=64)
  for (int b0 = 0; b0 < NBATCH; b0 += nb_grp) {
    k_dist<64><<<dim3(NTRI, 1, nb_grp), 256, 0, stream>>>(
        x1 + (size_t)b0 * NPTS * 64, dist);
    k_topk<<<dim3(NPTS / 4, nb_grp), 256, 0, stream>>>(dist,
                                                       knn + (size_t)b0 * NPTS * KNN);
  }
  k_t0<64, 64><<<dim3(NBATCH * NPTS / 128, 1), 256, 0, stream>>>(x1, w2, ybuf);
  k_t0<64, 64><<<dim3(NBATCH * NPTS / 128, 1), 256, 0, stream>>>(
      x1, w2 + (size_t)64 * 64, t0buf);
  k_egather<64><<<NBATCH * NPTS / 16, 256, 0, stream>>>(ybuf, t0buf, knn, g2, b2, x2);

  // ---- edge conv 3 (C=64 -> O=128)
  for (int b0 = 0; b0 < NBATCH; b0 += nb_grp) {
    k_dist<64><<<dim3(NTRI, 1, nb_grp), 256, 0, stream>>>(
        x2 + (size_t)b0 * NPTS * 64, dist);
    k_topk<<<dim3(NPTS / 4, nb_grp), 256, 0, stream>>>(dist,
                                                       knn + (size_t)b0 * NPTS * KNN);
  }
  k_t0<64, 128><<<dim3(NBATCH * NPTS / 128, 2), 256, 0, stream>>>(x2, w3, ybuf);
  k_t0<64, 128><<<dim3(NBATCH * NPTS / 128, 2), 256, 0, stream>>>(
      x2, w3 + (size_t)64 * 128, t0buf);
  k_egather<128><<<NBATCH * NPTS / 8, 256, 0, stream>>>(ybuf, t0buf, knn, g3, b3, x3);

  // ---- edge conv 4 (C=128 -> O=256)
  for (int b0 = 0; b0 < NBATCH; b0 += nb_grp) {
    k_dist<128><<<dim3(NTRI, 1, nb_grp), 256, 0, stream>>>(
        x3 + (size_t)b0 * NPTS * 128, dist);
    k_topk<<<dim3(NPTS / 4, nb_grp), 256, 0, stream>>>(dist,
                                                       knn + (size_t)b0 * NPTS * KNN);
  }
  k_t0<128, 256><<<dim3(NBATCH * NPTS / 128, 4), 256, 0, stream>>>(x3, w4, ybuf);
  k_t0<128, 256><<<dim3(NBATCH * NPTS / 128, 4), 256, 0, stream>>>(
      x3, w4 + (size_t)128 * 256, t0buf);
  k_egather<256><<<NBATCH * NPTS / 4, 256, 0, stream>>>(ybuf, t0buf, knn, g4, b4, x4);

  // ---- point MLP (split-bf16 MFMA GEMM) + pooling + head
  k_aprep<<<(16 * 1024 * 64 + 255) / 256, 256, 0, stream>>>(x1, x2, x3, x4, a5h, a5l);
  k_mlp5<<<dim3(NBATCH * NPTS / 128, 8), 256, 0, stream>>>(a5h, a5l, w5h, w5l, g5, b5,
                                                           pmax, psum);
  k_pool<<<(NBATCH * 1024 + 255) / 256, 256, 0, stream>>>(pmax, psum, pooled);
  k_head1<<<dim3(8, NBATCH), 256, 0, stream>>>(pooled, wl1, g6, b6, h1g);
  k_head23<<<NBATCH, 256, 0, stream>>>(h1g, wl2, bl2, g7, b7, wl3, bl3,
                                       (float*)d_out);
}